// Round 5
// baseline (1472.284 us; speedup 1.0000x reference)
//
#include <hip/hip_runtime.h>

#define NQ   128
#define DIM  256
#define WCN  306      // Ncam*P*L
#define NCAM 6
#define PP   17
#define LV   3
#define TT   4
#define PIX_ELEMS 104448          // 4*128*6*17*2 f32 elements (output 0)
#define OUT_CQ_OFF PIX_ELEMS
#define ROW  (2 * DIM)            // 512 f32 per query row: [cq | agg]

#define NREC (NQ * TT * NCAM * PP * LV)   // 156,672 records

// ---- workspace layout (bytes) ----
#define WB_OFF   0
#define WB_SZ    (NQ * WCN * 4)           // 156,672
#define CNT_OFF  156672
#define NBINS    624                      // l0: 24*20=480, l1: 24*5=120, l2: 24
#define R0_OFF   159232                   // 8-aligned
#define L0_CAP   768                      // lambda 435
#define R1_OFF   (R0_OFF + 480 * L0_CAP * 8)   // 3,108,352
#define L1_CAP   2304                     // lambda 1741
#define R2_OFF   (R1_OFF + 120 * L1_CAP * 8)   // 5,320,192
#define L2_CAP   10240                    // >= max possible 8704: always safe
#define PART_OFF (R2_OFF + 24 * L2_CAP * 8)    // 7,286,272
#define NSWEEP   4992
#define PART_SZ  ((size_t)NSWEEP * 2048 * 4)   // 40,894,464
#define WS_NEED3 ((size_t)PART_OFF + PART_SZ)  // 48,180,736

#define TS 648                            // LDS tile stride (pad vs 640)

typedef unsigned short u16;

// Native LDS f32 atomic add (fire-and-forget, no return, no CAS retry).
// NOTE (round-4 lesson): the "memory" clobber means any LDS *read* placed
// after a lds_fadd cannot be hoisted above it. Never interleave tile reads
// with lds_fadd calls — batch ALL reads first, then ALL adds, or each ref
// becomes a serial chain of dependent LDS round-trips (~2000 cy).
__device__ __forceinline__ void lds_fadd(float* p, float v) {
    unsigned off = (unsigned)(size_t)(void*)p;
    asm volatile("ds_add_f32 %0, %1" : : "v"(off), "v"(v) : "memory");
}

__device__ __forceinline__ void calc_tw(const float* ego, float* tw) {
    float e3 = ego[TT - 1];
    #pragma unroll
    for (int t = 0; t < TT; ++t) {
        float d = ego[t] - e3;
        tw[t] = expf(-d * d * 6.0f);   // exp(-td^2/DECAY*3), DECAY=0.5
    }
}

// ---------------------------------------------------------------------------
// K1 init: wbase (128 blk) + pixel copy (102 blk) + zero agg (32 blk) +
// zero bin counters (1 blk). Grid 263 x 320.
// ---------------------------------------------------------------------------
__global__ __launch_bounds__(320) void init_kernel(
    const float* __restrict__ cq, const float* __restrict__ Ww,
    const float* __restrict__ bw, const float* __restrict__ pixels,
    float* __restrict__ wbase, unsigned int* __restrict__ cnt,
    float* __restrict__ out)
{
    int bid = blockIdx.x, tid = threadIdx.x;
    if (bid < 128) {
        __shared__ float cqs[DIM];
        if (tid < DIM) cqs[tid] = cq[bid * DIM + tid];
        __syncthreads();
        if (tid < WCN) {
            float acc = bw[tid];
            #pragma unroll 8
            for (int d = 0; d < DIM; ++d) acc += cqs[d] * Ww[d * WCN + tid];
            wbase[bid * WCN + tid] = 1.0f / (1.0f + expf(-acc));
        }
    } else if (bid < 230) {
        if (tid < 256) {
            int v = (bid - 128) * 256 + tid;
            ((float4*)out)[v] = ((const float4*)pixels)[v];
        }
    } else if (bid < 262) {
        if (tid < 256) {
            int v = (bid - 230) * 256 + tid;
            int n  = v >> 6;
            int c4 = (v & 63) << 2;
            *(float4*)(out + OUT_CQ_OFF + n * ROW + DIM + c4) =
                make_float4(0.f, 0.f, 0.f, 0.f);
        }
    } else {
        for (int i = tid; i < NBINS; i += 320) cnt[i] = 0u;
    }
}

// ---------------------------------------------------------------------------
// K2 bin: 153 blocks x 1024 threads, one record/thread. Block-aggregated
// reservation: LDS histogram (native u32 ds atomics) -> ONE global atomicAdd
// per (block, bin) -> scattered record writes.
// ---------------------------------------------------------------------------
__global__ __launch_bounds__(1024) void bin_kernel(
    const float* __restrict__ pixels, const float* __restrict__ ego,
    const float* __restrict__ wbase, unsigned int* __restrict__ cnt,
    uint2* __restrict__ r0a, uint2* __restrict__ r1a, uint2* __restrict__ r2a)
{
    __shared__ unsigned int lcnt[NBINS];
    __shared__ unsigned int gbs[NBINS];

    int tid = threadIdx.x;
    int r = blockIdx.x * 1024 + tid;
    if (tid < NBINS) lcnt[tid] = 0u;

    int l = r % 3;  int q1 = r / 3;
    int p = q1 % PP; q1 /= PP;
    int cam = q1 % NCAM; q1 /= NCAM;
    int n = q1 % NQ;  int t = q1 / NQ;     // t in [0,4)

    float e3 = ego[TT - 1];
    float dt = ego[t] - e3;
    float tw = expf(-dt * dt * 6.0f);
    int j = cam * (PP * LV) + p * LV + l;
    float w = wbase[n * WCN + j] * tw;
    int pidx = (((t * NQ + n) * NCAM + cam) * PP + p) << 1;
    float px0 = pixels[pidx], px1 = pixels[pidx + 1];
    if (px0 < 0.f) w = 0.f;

    int W_ = (l == 0) ? 160 : ((l == 1) ? 80 : 40);
    int H_ = (l == 0) ? 64  : ((l == 1) ? 32 : 16);
    float ix = px0 * (float)(W_ - 1);
    float iy = px1 * (float)(H_ - 1);
    float x0f = floorf(ix), y0f = floorf(iy);
    float wx1 = ix - x0f, wy1 = iy - y0f;
    float wx0 = 1.f - wx1, wy0 = 1.f - wy1;
    int x0 = (int)x0f, y0 = (int)y0f;
    int x1 = x0 + 1,  y1 = y0 + 1;
    bool vx0 = (x0 >= 0) & (x0 < W_), vx1 = (x1 >= 0) & (x1 < W_);
    bool vy0 = (y0 >= 0) & (y0 < H_), vy1 = (y1 >= 0) & (y1 < H_);
    int cx0 = min(max(x0, 0), W_ - 1), cx1 = min(max(x1, 0), W_ - 1);
    int cy0 = min(max(y0, 0), H_ - 1), cy1 = min(max(y1, 0), H_ - 1);

    int pos_[4];
    float wq_[4];
    pos_[0] = cy0 * W_ + cx0;  wq_[0] = w * wy0 * wx0 * ((vx0 & vy0) ? 1.f : 0.f);
    pos_[1] = cy0 * W_ + cx1;  wq_[1] = w * wy0 * wx1 * ((vx1 & vy0) ? 1.f : 0.f);
    pos_[2] = cy1 * W_ + cx0;  wq_[2] = w * wy1 * wx0 * ((vx0 & vy1) ? 1.f : 0.f);
    pos_[3] = cy1 * W_ + cx1;  wq_[3] = w * wy1 * wx1 * ((vx1 & vy1) ? 1.f : 0.f);

    int plane = cam * TT + t;
    int binq[4];
    unsigned int lslot[4];

    __syncthreads();   // lcnt zeroed before local reservation

    #pragma unroll
    for (int q = 0; q < 4; ++q) {
        binq[q] = -1;
        if (wq_[q] != 0.f) {
            int b;
            if (l == 0)      b = plane * 20 + (pos_[q] >> 9);
            else if (l == 1) b = 480 + plane * 5 + (pos_[q] >> 9);
            else             b = 600 + plane;
            lslot[q] = atomicAdd(&lcnt[b], 1u);
            binq[q] = b;
        }
    }
    __syncthreads();

    if (tid < NBINS) {
        unsigned int c = lcnt[tid];
        gbs[tid] = c ? atomicAdd(&cnt[tid], c) : 0u;
    }
    __syncthreads();

    #pragma unroll
    for (int q = 0; q < 4; ++q) {
        int b = binq[q];
        if (b < 0) continue;
        unsigned int idx = gbs[b] + lslot[q];
        unsigned int pk = ((unsigned)pos_[q] << 7) | (unsigned)n;
        uint2 rec = make_uint2(pk, __float_as_uint(wq_[q]));
        if (b < 480) {
            if (idx < L0_CAP) r0a[(size_t)b * L0_CAP + idx] = rec;
        } else if (b < 600) {
            if (idx < L1_CAP) r1a[(size_t)(b - 480) * L1_CAP + idx] = rec;
        } else {
            if (idx < L2_CAP) r2a[(size_t)(b - 600) * L2_CAP + idx] = rec;
        }
    }
}

// ---------------------------------------------------------------------------
// K3 sweep: block = (level, plane, 16-channel tile, window-chunk / ref-chunk).
// Stream the f32 feature tile (16c x <=640pos) into LDS once (coalesced).
// Per ref: BATCH all 16 tile reads into registers (one lgkmcnt wait), THEN
// issue 16 ds_add_f32 back-to-back (round-4 fix: no read-add interleave, no
// 16-deep dependent LDS chain). Partials stored plain to part[bid].
// Grid 4992 x 512. LDS = 41,472 + 8,704 = 50,176 B -> 3 blocks/CU.
// ---------------------------------------------------------------------------
__global__ __launch_bounds__(512) void sweep_kernel(
    const float* __restrict__ f0, const float* __restrict__ f1,
    const float* __restrict__ f2, const unsigned int* __restrict__ cnt,
    const uint2* __restrict__ r0a, const uint2* __restrict__ r1a,
    const uint2* __restrict__ r2a, float* __restrict__ part)
{
    __shared__ float tile[16 * TS];     // 41,472 B
    __shared__ float accum[128 * 17];   //  8,704 B

    int bid = blockIdx.x, tid = threadIdx.x;
    int wv = tid >> 6, lane = tid & 63;

    int plane, ctile, HW, win0, nwin, wlen, cntbase, wins, cap, chunk = -1;
    const uint2* refs; const float* fb;
    if (bid < 1536) {
        plane = bid >> 6; int rr = bid & 63; ctile = rr >> 2; int wc = rr & 3;
        win0 = wc * 5; nwin = 5; wlen = 512;
        cntbase = 0; wins = 20; cap = L0_CAP; refs = r0a; fb = f0; HW = 10240;
    } else if (bid < 3456) {
        int b = bid - 1536; plane = b / 80; int rr = b % 80; ctile = rr / 5;
        win0 = rr % 5; nwin = 1; wlen = 512;
        cntbase = 480; wins = 5; cap = L1_CAP; refs = r1a; fb = f1; HW = 2560;
    } else {
        int b = bid - 3456; plane = b >> 6; int rr = b & 63;
        ctile = rr >> 2; chunk = rr & 3;
        win0 = 0; nwin = 1; wlen = 640;
        cntbase = 600; wins = 1; cap = L2_CAP; refs = r2a; fb = f2; HW = 640;
    }
    int c0 = ctile << 4;

    for (int i = tid; i < 128 * 17; i += 512) accum[i] = 0.f;

    int cq = tid >> 5, qq = tid & 31;   // tile loader: 16 c-rows x 32 loaders

    for (int w = 0; w < nwin; ++w) {
        int win = win0 + w;
        int pos0 = win * wlen;          // l2: always 0

        const float* src = fb + ((size_t)((plane << 8) + c0 + cq)) * HW + pos0;
        if (wlen == 512) {
            #pragma unroll
            for (int k = 0; k < 4; ++k) {
                int p = (qq << 4) + (k << 2);
                *(float4*)&tile[cq * TS + p] = *(const float4*)(src + p);
            }
        } else {
            #pragma unroll
            for (int k = 0; k < 5; ++k) {
                int p = qq * 20 + (k << 2);
                *(float4*)&tile[cq * TS + p] = *(const float4*)(src + p);
            }
        }
        __syncthreads();

        int gb = cntbase + plane * wins + win;
        int nrefs = min((int)cnt[gb], cap);
        const uint2* rb = refs + (size_t)(plane * wins + win) * cap;
        int s0 = 0, s1 = nrefs;
        if (chunk >= 0) {
            int len = (nrefs + 3) >> 2;
            s0 = chunk * len; s1 = min(s0 + len, nrefs);
        }
        int m = s1 - s0;
        int nb = (m + 63) >> 6;
        for (int b = wv; b < nb; b += 8) {
            int s = s0 + (b << 6) + lane;
            uint2 rv = (s < s1) ? rb[s]
                                : make_uint2((unsigned)pos0 << 7, 0u);
            float wgt = __uint_as_float(rv.y);
            int nn = (int)(rv.x & 127u);
            int posl = (int)(rv.x >> 7) - pos0;
            float* ac = accum + nn * 17;
            const float* tl = tile + posl;
            // Phase 1: all 16 tile reads -> registers (independent ds_reads,
            // single waitcnt). MUST complete before the first lds_fadd's
            // "memory" clobber, or the reads serialize against the adds.
            float prod[16];
            #pragma unroll
            for (int c = 0; c < 16; ++c)
                prod[c] = wgt * tl[c * TS];
            // Phase 2: 16 fire-and-forget ds_add_f32, issued back-to-back.
            #pragma unroll
            for (int c = 0; c < 16; ++c)
                lds_fadd(ac + c, prod[c]);
        }
        __syncthreads();
    }

    // write per-block partials (plain coalesced stores, no atomics)
    float* pp = part + (size_t)bid * 2048;
    for (int i = tid; i < 2048; i += 512) {
        int nn = i >> 4, c = i & 15;
        pp[i] = accum[nn * 17 + c];
    }
}

// ---------------------------------------------------------------------------
// K3b reduce: agg[n, c0+c] = sum of the 312 partials that cover ctile.
// Grid 256 x 128: block = (ctile, 128-elem segment). Fully coalesced.
// ---------------------------------------------------------------------------
__global__ __launch_bounds__(128) void reduce_kernel(
    const float* __restrict__ part, float* __restrict__ out)
{
    int bid = blockIdx.x;
    int ctile = bid >> 4;
    int seg = bid & 15;
    int e = seg * 128 + threadIdx.x;      // 0..2047
    int nn = e >> 4, c = e & 15;

    float acc = 0.f;
    #pragma unroll 4
    for (int plane = 0; plane < 24; ++plane) {
        #pragma unroll
        for (int wc = 0; wc < 4; ++wc)
            acc += part[(size_t)(plane * 64 + ctile * 4 + wc) * 2048 + e];
    }
    #pragma unroll 4
    for (int plane = 0; plane < 24; ++plane) {
        #pragma unroll
        for (int win = 0; win < 5; ++win)
            acc += part[(size_t)(1536 + plane * 80 + ctile * 5 + win) * 2048 + e];
    }
    #pragma unroll 4
    for (int plane = 0; plane < 24; ++plane) {
        #pragma unroll
        for (int ch = 0; ch < 4; ++ch)
            acc += part[(size_t)(3456 + plane * 64 + ctile * 4 + ch) * 2048 + e];
    }
    out[OUT_CQ_OFF + nn * ROW + DIM + (ctile << 4) + c] = acc;
}

// ---------------------------------------------------------------------------
// Fallback path (tiny ws): copy/zero + channel-major direct gather (R3).
// ---------------------------------------------------------------------------
__global__ __launch_bounds__(256) void copy_zero_kernel(
    const float* __restrict__ pixels, float* __restrict__ out)
{
    int bid = blockIdx.x, tid = threadIdx.x;
    if (bid < 102) {
        int v = bid * 256 + tid;
        ((float4*)out)[v] = ((const float4*)pixels)[v];
    } else {
        int v = (bid - 102) * 256 + tid;
        int n  = v >> 6;
        int c4 = (v & 63) << 2;
        float4* dst = (float4*)(out + OUT_CQ_OFF + n * ROW + DIM + c4);
        *dst = make_float4(0.f, 0.f, 0.f, 0.f);
    }
}

__global__ __launch_bounds__(256) void gather_kernel(
    const float* __restrict__ cq, const float* __restrict__ pixels,
    const float* __restrict__ ego, const float* __restrict__ Ww,
    const float* __restrict__ bw,
    const float* __restrict__ f0, const float* __restrict__ f1,
    const float* __restrict__ f2, float* __restrict__ out)
{
    int bid = blockIdx.x;
    int n   = bid & (NQ - 1);
    int g   = bid >> 7;
    int l   = g / NCAM;
    int cam = g - l * NCAM;
    int tid = threadIdx.x;

    __shared__ float cqs[DIM];
    __shared__ float ws[PP];
    __shared__ float pix[TT * PP * 2];
    __shared__ int4   offs4[TT * PP];
    __shared__ float4 wt4[TT * PP];

    cqs[tid] = cq[n * DIM + tid];
    if (tid < TT * PP * 2) {
        int t = tid / (PP * 2);
        int r = tid - t * (PP * 2);
        int p = r >> 1, comp = r & 1;
        pix[tid] = pixels[((((t * NQ + n) * NCAM + cam) * PP + p) << 1) + comp];
    }
    __syncthreads();

    if (tid < PP) {
        int j = cam * (PP * LV) + tid * LV + l;
        float acc = bw[j];
        #pragma unroll 8
        for (int d = 0; d < DIM; ++d) acc += cqs[d] * Ww[d * WCN + j];
        ws[tid] = 1.0f / (1.0f + expf(-acc));
    }
    __syncthreads();

    const int W_ = (l == 0) ? 160 : ((l == 1) ? 80 : 40);
    const int H_ = (l == 0) ? 64  : ((l == 1) ? 32 : 16);
    const int HW = W_ * H_;

    if (tid < TT * PP) {
        int t = tid / PP, p = tid - t * PP;
        float twl[TT]; calc_tw(ego, twl);
        float px0 = pix[(t * PP + p) * 2];
        float px1 = pix[(t * PP + p) * 2 + 1];
        float w = ws[p] * twl[t];
        if (px0 < 0.f) w = 0.f;
        float ix = px0 * (float)(W_ - 1);
        float iy = px1 * (float)(H_ - 1);
        float x0f = floorf(ix), y0f = floorf(iy);
        float wx1 = ix - x0f, wy1 = iy - y0f;
        float wx0 = 1.f - wx1, wy0 = 1.f - wy1;
        int x0 = (int)x0f, y0 = (int)y0f;
        int x1 = x0 + 1,  y1 = y0 + 1;
        bool vx0 = (x0 >= 0) & (x0 < W_), vx1 = (x1 >= 0) & (x1 < W_);
        bool vy0 = (y0 >= 0) & (y0 < H_), vy1 = (y1 >= 0) & (y1 < H_);
        int cx0 = min(max(x0, 0), W_ - 1), cx1 = min(max(x1, 0), W_ - 1);
        int cy0 = min(max(y0, 0), H_ - 1), cy1 = min(max(y1, 0), H_ - 1);
        offs4[tid] = make_int4(cy0 * W_ + cx0, cy0 * W_ + cx1,
                               cy1 * W_ + cx0, cy1 * W_ + cx1);
        wt4[tid] = make_float4(w * wy0 * wx0 * ((vx0 & vy0) ? 1.f : 0.f),
                               w * wy0 * wx1 * ((vx1 & vy0) ? 1.f : 0.f),
                               w * wy1 * wx0 * ((vx0 & vy1) ? 1.f : 0.f),
                               w * wy1 * wx1 * ((vx1 & vy1) ? 1.f : 0.f));
    }
    __syncthreads();

    const float* fbase = (l == 0) ? f0 : ((l == 1) ? f1 : f2);
    const float* base_c = fbase + (size_t)(cam * TT * DIM + tid) * (size_t)HW;

    float acc = 0.f;
    #pragma unroll
    for (int t = 0; t < TT; ++t) {
        const float* base = base_c + (size_t)t * (size_t)(DIM * HW);
        #pragma unroll 4
        for (int p = 0; p < PP; ++p) {
            int rr = t * PP + p;
            int4 o = offs4[rr];
            float4 w4 = wt4[rr];
            acc += w4.x * base[o.x] + w4.y * base[o.y]
                 + w4.z * base[o.z] + w4.w * base[o.w];
        }
    }
    atomicAdd(&out[OUT_CQ_OFF + n * ROW + DIM + tid], acc);
}

// ---------------------------------------------------------------------------
// K4 epilogue: recompute den, divide agg in place, write cq.
// ---------------------------------------------------------------------------
__global__ __launch_bounds__(512) void epilogue_kernel(
    const float* __restrict__ cq, const float* __restrict__ pixels,
    const float* __restrict__ ego, const float* __restrict__ Ww,
    const float* __restrict__ bw, float* __restrict__ out)
{
    int n = blockIdx.x, tid = threadIdx.x;
    __shared__ float cqs[DIM];
    __shared__ float red[512];
    __shared__ float dsh;

    if (tid < DIM) cqs[tid] = cq[n * DIM + tid];
    __syncthreads();

    float tw[TT]; calc_tw(ego, tw);

    float denj = 0.f;
    if (tid < WCN) {
        int j = tid;
        float acc = bw[j];
        #pragma unroll 8
        for (int d = 0; d < DIM; ++d) acc += cqs[d] * Ww[d * WCN + j];
        float sig = 1.0f / (1.0f + expf(-acc));
        int cam = j / (PP * LV);
        int rem = j - cam * (PP * LV);
        int p   = rem / LV;
        float s = 0.f;
        #pragma unroll
        for (int t = 0; t < TT; ++t) {
            float px0 = pixels[(((t * NQ + n) * NCAM + cam) * PP + p) << 1];
            s += (px0 < 0.f) ? 0.f : tw[t];
        }
        denj = sig * s;
    }
    red[tid] = denj;
    __syncthreads();
    for (int off = 256; off > 0; off >>= 1) {
        if (tid < off) red[tid] += red[tid + off];
        __syncthreads();
    }
    if (tid == 0) dsh = fmaxf(red[0], 1e-6f);
    __syncthreads();

    float den = dsh;
    float* row = out + OUT_CQ_OFF + n * ROW;
    if (tid < DIM) {
        row[tid] = cqs[tid];
        row[DIM + tid] /= den;
    }
}

extern "C" void kernel_launch(void* const* d_in, const int* in_sizes, int n_in,
                              void* d_out, int out_size, void* d_ws, size_t ws_size,
                              hipStream_t stream)
{
    const float* cq     = (const float*)d_in[0];
    const float* pixels = (const float*)d_in[1];
    const float* ego    = (const float*)d_in[2];
    const float* Ww     = (const float*)d_in[3];
    const float* bw     = (const float*)d_in[4];
    const float* f0     = (const float*)d_in[5];
    const float* f1     = (const float*)d_in[6];
    const float* f2     = (const float*)d_in[7];

    float* out = (float*)d_out;
    bool fast = (d_ws != nullptr) && (ws_size >= WS_NEED3);

    if (fast) {
        float*        wbase = (float*)((char*)d_ws + WB_OFF);
        unsigned int* cnt   = (unsigned int*)((char*)d_ws + CNT_OFF);
        uint2*        r0a   = (uint2*)((char*)d_ws + R0_OFF);
        uint2*        r1a   = (uint2*)((char*)d_ws + R1_OFF);
        uint2*        r2a   = (uint2*)((char*)d_ws + R2_OFF);
        float*        part  = (float*)((char*)d_ws + PART_OFF);

        init_kernel<<<263, 320, 0, stream>>>(cq, Ww, bw, pixels, wbase, cnt, out);
        bin_kernel<<<NREC / 1024, 1024, 0, stream>>>(pixels, ego, wbase, cnt,
                                                     r0a, r1a, r2a);
        sweep_kernel<<<NSWEEP, 512, 0, stream>>>(f0, f1, f2, cnt,
                                                 r0a, r1a, r2a, part);
        reduce_kernel<<<256, 128, 0, stream>>>(part, out);
    } else {
        copy_zero_kernel<<<134, 256, 0, stream>>>(pixels, out);
        gather_kernel<<<18 * NQ, 256, 0, stream>>>(cq, pixels, ego, Ww, bw,
                                                   f0, f1, f2, out);
    }

    epilogue_kernel<<<NQ, 512, 0, stream>>>(cq, pixels, ego, Ww, bw, out);
}

// Round 6
// 490.213 us; speedup vs baseline: 3.0034x; 3.0034x over previous
//
#include <hip/hip_runtime.h>

#define NQ   128
#define DIM  256
#define WCN  306      // Ncam*P*L
#define NCAM 6
#define PP   17
#define LV   3
#define TT   4
#define PIX_ELEMS 104448          // 4*128*6*17*2 f32 elements (output 0)
#define OUT_CQ_OFF PIX_ELEMS
#define ROW  (2 * DIM)            // 512 f32 per query row: [cq | agg]

// ---- transposed-feature geometry (channel-last bf16 in d_ws) ----
#define SPAT_L0 245760            // 24 planes * 10240
#define SPAT_L1 61440             // 24 * 2560
#define SPAT_L2 15360             // 24 * 640
#define SPAT_TOTAL (SPAT_L0 + SPAT_L1 + SPAT_L2)   // 322560
#define TF_ELEMS ((size_t)SPAT_TOTAL * 256)        // 82,575,360 bf16
#define TF_BYTES (TF_ELEMS * 2)                    // 165,150,720 B
#define WB_BYTES ((size_t)NQ * WCN * 4)            // 156,672 B
#define WS_NEED  (TF_BYTES + WB_BYTES)

#define SCH 12                    // gather chunks per query
#define RPB 102                   // records per gather block (1224/12)

typedef unsigned short u16;

__device__ __forceinline__ float b2f(u16 u) {
    union { unsigned int i; float f; } v;
    v.i = ((unsigned int)u) << 16;
    return v.f;
}
__device__ __forceinline__ u16 f2b(float f) {
    union { float f; unsigned int i; } v;
    v.f = f;
    unsigned int x = v.i;
    return (u16)((x + 0x7FFFu + ((x >> 16) & 1u)) >> 16);
}
__device__ __forceinline__ void calc_tw(const float* ego, float* tw) {
    float e3 = ego[TT - 1];
    #pragma unroll
    for (int t = 0; t < TT; ++t) {
        float d = ego[t] - e3;
        tw[t] = expf(-d * d * 6.0f);   // exp(-td^2/DECAY*3), DECAY=0.5
    }
}

// ---------------------------------------------------------------------------
// K1 init (merged): wbase GEMV+sigmoid (blocks 0..127), pixel copy
// (128..229), zero agg slots (230..261). Grid 262 x 320. Saves one launch
// vs the round-0 champion (prep_wbase + copy_zero).
// ---------------------------------------------------------------------------
__global__ __launch_bounds__(320) void init_kernel(
    const float* __restrict__ cq, const float* __restrict__ Ww,
    const float* __restrict__ bw, const float* __restrict__ pixels,
    float* __restrict__ wbase, float* __restrict__ out)
{
    int bid = blockIdx.x, tid = threadIdx.x;
    if (bid < 128) {
        __shared__ float cqs[DIM];
        if (tid < DIM) cqs[tid] = cq[bid * DIM + tid];
        __syncthreads();
        if (tid < WCN) {
            float acc = bw[tid];
            #pragma unroll 8
            for (int d = 0; d < DIM; ++d) acc += cqs[d] * Ww[d * WCN + tid];
            wbase[bid * WCN + tid] = 1.0f / (1.0f + expf(-acc));
        }
    } else if (bid < 230) {
        if (tid < 256) {
            int v = (bid - 128) * 256 + tid;
            ((float4*)out)[v] = ((const float4*)pixels)[v];
        }
    } else {
        if (tid < 256) {
            int v = (bid - 230) * 256 + tid;
            int n  = v >> 6;
            int c4 = (v & 63) << 2;
            *(float4*)(out + OUT_CQ_OFF + n * ROW + DIM + c4) =
                make_float4(0.f, 0.f, 0.f, 0.f);
        }
    }
}

// ---------------------------------------------------------------------------
// Kernel T: transpose [cam*t][C][H*W] f32 -> [cam*t][H*W][C] bf16.
// 64x64 tiles via LDS. Grid = 15360 (l0) + 3840 (l1) + 960 (l2) = 20160.
// (Verbatim from the 492 us champion.)
// ---------------------------------------------------------------------------
__global__ __launch_bounds__(256) void transpose_kernel(
    const float* __restrict__ f0, const float* __restrict__ f1,
    const float* __restrict__ f2, u16* __restrict__ tf)
{
    __shared__ float lds[64][65];   // [hw_local][c_local], pad 65
    int bid = blockIdx.x, tid = threadIdx.x;
    int plane, ctile, hwtile, HW, spat_base;
    const float* src;
    if (bid < 15360) {
        HW = 10240; src = f0; spat_base = 0;
        plane = bid / 640; int r = bid - plane * 640; ctile = r / 160; hwtile = r - ctile * 160;
    } else if (bid < 19200) {
        int b = bid - 15360; HW = 2560; src = f1; spat_base = SPAT_L0;
        plane = b / 160; int r = b - plane * 160; ctile = r / 40; hwtile = r - ctile * 40;
    } else {
        int b = bid - 19200; HW = 640; src = f2; spat_base = SPAT_L0 + SPAT_L1;
        plane = b / 40; int r = b - plane * 40; ctile = r / 10; hwtile = r - ctile * 10;
    }
    int hw0 = hwtile * 64;
    int c0  = ctile * 64;

    // read: coalesced float4 along hw; thread (cl = tid/16, hl = (tid%16)*4)
    const float* sp = src + ((size_t)plane * 256 + c0) * HW + hw0;
    int cl = tid >> 4;
    int hl = (tid & 15) << 2;
    #pragma unroll
    for (int pass = 0; pass < 4; ++pass) {
        int c = pass * 16 + cl;
        float4 v = *(const float4*)(sp + (size_t)c * HW + hl);
        lds[hl + 0][c] = v.x; lds[hl + 1][c] = v.y;
        lds[hl + 2][c] = v.z; lds[hl + 3][c] = v.w;
    }
    __syncthreads();

    // write: coalesced ushort4 along c; thread (hr = tid/16, c4 = (tid%16)*4)
    int hr = tid >> 4;
    int c4 = (tid & 15) << 2;
    u16* dp = tf + ((size_t)(spat_base + plane * HW + hw0)) * 256 + c0;
    #pragma unroll
    for (int pass = 0; pass < 4; ++pass) {
        int hw = pass * 16 + hr;
        ushort4 o = make_ushort4(f2b(lds[hw][c4 + 0]), f2b(lds[hw][c4 + 1]),
                                 f2b(lds[hw][c4 + 2]), f2b(lds[hw][c4 + 3]));
        *(ushort4*)(dp + (size_t)hw * 256 + c4) = o;
    }
}

// ---------------------------------------------------------------------------
// Kernel G: coalesced gather from channel-last bf16 features.
// Grid = NQ * SCH blocks; 256 threads = 4 waves. Per block: precompute RPB
// records' corner spatial offsets + validity-folded weights in LDS, then each
// wave processes records i == wave (mod 4): 4 corners x one ushort4 wave-load
// (512 B coalesced) + FMA into acc[4]. Cross-wave LDS reduce, atomicAdd.
// (Verbatim from the 492 us champion. Lane = channel: NO cross-lane scatter,
// register accumulation — this is why it doesn't hit the sweep's stall.)
// ---------------------------------------------------------------------------
__global__ __launch_bounds__(256) void gather_tr_kernel(
    const float* __restrict__ pixels, const float* __restrict__ ego,
    const float* __restrict__ wbase, const u16* __restrict__ tf,
    float* __restrict__ out)
{
    int bid = blockIdx.x;
    int n = bid / SCH;
    int chunk = bid - n * SCH;
    int tid = threadIdx.x;

    __shared__ int   offs[RPB][4];
    __shared__ float wts[RPB][4];
    __shared__ float red[4][DIM];

    if (tid < RPB) {
        int r = chunk * RPB + tid;
        int t = r / WCN;  int j = r - t * WCN;
        int cam = j / 51; int rem = j - cam * 51;
        int p = rem / 3;  int l = rem - p * 3;
        float e3 = ego[TT - 1];
        float dt = ego[t] - e3;
        float tw = expf(-dt * dt * 6.0f);
        int pidx = (((t * NQ + n) * NCAM + cam) * PP + p) << 1;
        float px0 = pixels[pidx], px1 = pixels[pidx + 1];
        float w = wbase[n * WCN + j] * tw;
        if (px0 < 0.f) w = 0.f;
        int W_ = (l == 0) ? 160 : ((l == 1) ? 80 : 40);
        int H_ = (l == 0) ? 64  : ((l == 1) ? 32 : 16);
        int HW = W_ * H_;
        int sb = (l == 0) ? 0 : ((l == 1) ? SPAT_L0 : (SPAT_L0 + SPAT_L1));
        float ix = px0 * (float)(W_ - 1);     // == (gx+1)/2*(W-1)
        float iy = px1 * (float)(H_ - 1);
        float x0f = floorf(ix), y0f = floorf(iy);
        float wx1 = ix - x0f, wy1 = iy - y0f;
        float wx0 = 1.f - wx1, wy0 = 1.f - wy1;
        int x0 = (int)x0f, y0 = (int)y0f;
        int x1 = x0 + 1,  y1 = y0 + 1;
        bool vx0 = (x0 >= 0) & (x0 < W_), vx1 = (x1 >= 0) & (x1 < W_);
        bool vy0 = (y0 >= 0) & (y0 < H_), vy1 = (y1 >= 0) & (y1 < H_);
        int cx0 = min(max(x0, 0), W_ - 1), cx1 = min(max(x1, 0), W_ - 1);
        int cy0 = min(max(y0, 0), H_ - 1), cy1 = min(max(y1, 0), H_ - 1);
        int base = sb + (cam * TT + t) * HW;
        offs[tid][0] = base + cy0 * W_ + cx0;
        offs[tid][1] = base + cy0 * W_ + cx1;
        offs[tid][2] = base + cy1 * W_ + cx0;
        offs[tid][3] = base + cy1 * W_ + cx1;
        wts[tid][0] = w * wy0 * wx0 * ((vx0 & vy0) ? 1.f : 0.f);
        wts[tid][1] = w * wy0 * wx1 * ((vx1 & vy0) ? 1.f : 0.f);
        wts[tid][2] = w * wy1 * wx0 * ((vx0 & vy1) ? 1.f : 0.f);
        wts[tid][3] = w * wy1 * wx1 * ((vx1 & vy1) ? 1.f : 0.f);
    }
    __syncthreads();

    int wv   = tid >> 6;
    int lane = tid & 63;
    float acc0 = 0.f, acc1 = 0.f, acc2 = 0.f, acc3 = 0.f;
    for (int i = wv; i < RPB; i += 4) {
        #pragma unroll
        for (int q = 0; q < 4; ++q) {
            float wq = wts[i][q];
            ushort4 v = *(const ushort4*)(tf + (size_t)offs[i][q] * 256 + (lane << 2));
            acc0 += wq * b2f(v.x);
            acc1 += wq * b2f(v.y);
            acc2 += wq * b2f(v.z);
            acc3 += wq * b2f(v.w);
        }
    }
    int cb = lane << 2;
    red[wv][cb + 0] = acc0; red[wv][cb + 1] = acc1;
    red[wv][cb + 2] = acc2; red[wv][cb + 3] = acc3;
    __syncthreads();
    if (tid < DIM) {
        float s = red[0][tid] + red[1][tid] + red[2][tid] + red[3][tid];
        atomicAdd(&out[OUT_CQ_OFF + n * ROW + DIM + tid], s);
    }
}

// ---------------------------------------------------------------------------
// Fallback gather (channel-major): one block per (g, n), g = (l, cam).
// ---------------------------------------------------------------------------
__global__ __launch_bounds__(256) void copy_zero_kernel(
    const float* __restrict__ pixels, float* __restrict__ out)
{
    int bid = blockIdx.x, tid = threadIdx.x;
    if (bid < 102) {
        int v = bid * 256 + tid;
        ((float4*)out)[v] = ((const float4*)pixels)[v];
    } else {
        int v = (bid - 102) * 256 + tid;
        int n  = v >> 6;
        int c4 = (v & 63) << 2;
        float4* dst = (float4*)(out + OUT_CQ_OFF + n * ROW + DIM + c4);
        *dst = make_float4(0.f, 0.f, 0.f, 0.f);
    }
}

__global__ __launch_bounds__(256) void gather_kernel(
    const float* __restrict__ cq, const float* __restrict__ pixels,
    const float* __restrict__ ego, const float* __restrict__ Ww,
    const float* __restrict__ bw,
    const float* __restrict__ f0, const float* __restrict__ f1,
    const float* __restrict__ f2, float* __restrict__ out)
{
    int bid = blockIdx.x;
    int n   = bid & (NQ - 1);
    int g   = bid >> 7;
    int l   = g / NCAM;
    int cam = g - l * NCAM;
    int tid = threadIdx.x;

    __shared__ float cqs[DIM];
    __shared__ float ws[PP];
    __shared__ float pix[TT * PP * 2];
    __shared__ int4   offs4[TT * PP];
    __shared__ float4 wt4[TT * PP];

    cqs[tid] = cq[n * DIM + tid];
    if (tid < TT * PP * 2) {
        int t = tid / (PP * 2);
        int r = tid - t * (PP * 2);
        int p = r >> 1, comp = r & 1;
        pix[tid] = pixels[((((t * NQ + n) * NCAM + cam) * PP + p) << 1) + comp];
    }
    __syncthreads();

    if (tid < PP) {
        int j = cam * (PP * LV) + tid * LV + l;
        float acc = bw[j];
        #pragma unroll 8
        for (int d = 0; d < DIM; ++d) acc += cqs[d] * Ww[d * WCN + j];
        ws[tid] = 1.0f / (1.0f + expf(-acc));
    }
    __syncthreads();

    const int W_ = (l == 0) ? 160 : ((l == 1) ? 80 : 40);
    const int H_ = (l == 0) ? 64  : ((l == 1) ? 32 : 16);
    const int HW = W_ * H_;

    if (tid < TT * PP) {
        int t = tid / PP, p = tid - t * PP;
        float twl[TT]; calc_tw(ego, twl);
        float px0 = pix[(t * PP + p) * 2];
        float px1 = pix[(t * PP + p) * 2 + 1];
        float w = ws[p] * twl[t];
        if (px0 < 0.f) w = 0.f;
        float ix = px0 * (float)(W_ - 1);
        float iy = px1 * (float)(H_ - 1);
        float x0f = floorf(ix), y0f = floorf(iy);
        float wx1 = ix - x0f, wy1 = iy - y0f;
        float wx0 = 1.f - wx1, wy0 = 1.f - wy1;
        int x0 = (int)x0f, y0 = (int)y0f;
        int x1 = x0 + 1,  y1 = y0 + 1;
        bool vx0 = (x0 >= 0) & (x0 < W_), vx1 = (x1 >= 0) & (x1 < W_);
        bool vy0 = (y0 >= 0) & (y0 < H_), vy1 = (y1 >= 0) & (y1 < H_);
        int cx0 = min(max(x0, 0), W_ - 1), cx1 = min(max(x1, 0), W_ - 1);
        int cy0 = min(max(y0, 0), H_ - 1), cy1 = min(max(y1, 0), H_ - 1);
        offs4[tid] = make_int4(cy0 * W_ + cx0, cy0 * W_ + cx1,
                               cy1 * W_ + cx0, cy1 * W_ + cx1);
        wt4[tid] = make_float4(w * wy0 * wx0 * ((vx0 & vy0) ? 1.f : 0.f),
                               w * wy0 * wx1 * ((vx1 & vy0) ? 1.f : 0.f),
                               w * wy1 * wx0 * ((vx0 & vy1) ? 1.f : 0.f),
                               w * wy1 * wx1 * ((vx1 & vy1) ? 1.f : 0.f));
    }
    __syncthreads();

    const float* fbase = (l == 0) ? f0 : ((l == 1) ? f1 : f2);
    const float* base_c = fbase + (size_t)(cam * TT * DIM + tid) * (size_t)HW;

    float acc = 0.f;
    #pragma unroll
    for (int t = 0; t < TT; ++t) {
        const float* base = base_c + (size_t)t * (size_t)(DIM * HW);
        #pragma unroll 4
        for (int p = 0; p < PP; ++p) {
            int rr = t * PP + p;
            int4 o = offs4[rr];
            float4 w4 = wt4[rr];
            acc += w4.x * base[o.x] + w4.y * base[o.y]
                 + w4.z * base[o.z] + w4.w * base[o.w];
        }
    }
    atomicAdd(&out[OUT_CQ_OFF + n * ROW + DIM + tid], acc);
}

// ---------------------------------------------------------------------------
// K4 epilogue: recompute den, divide agg in place, write cq.
// ---------------------------------------------------------------------------
__global__ __launch_bounds__(512) void epilogue_kernel(
    const float* __restrict__ cq, const float* __restrict__ pixels,
    const float* __restrict__ ego, const float* __restrict__ Ww,
    const float* __restrict__ bw, float* __restrict__ out)
{
    int n = blockIdx.x, tid = threadIdx.x;
    __shared__ float cqs[DIM];
    __shared__ float red[512];
    __shared__ float dsh;

    if (tid < DIM) cqs[tid] = cq[n * DIM + tid];
    __syncthreads();

    float tw[TT]; calc_tw(ego, tw);

    float denj = 0.f;
    if (tid < WCN) {
        int j = tid;
        float acc = bw[j];
        #pragma unroll 8
        for (int d = 0; d < DIM; ++d) acc += cqs[d] * Ww[d * WCN + j];
        float sig = 1.0f / (1.0f + expf(-acc));
        int cam = j / (PP * LV);
        int rem = j - cam * (PP * LV);
        int p   = rem / LV;
        float s = 0.f;
        #pragma unroll
        for (int t = 0; t < TT; ++t) {
            float px0 = pixels[(((t * NQ + n) * NCAM + cam) * PP + p) << 1];
            s += (px0 < 0.f) ? 0.f : tw[t];
        }
        denj = sig * s;
    }
    red[tid] = denj;
    __syncthreads();
    for (int off = 256; off > 0; off >>= 1) {
        if (tid < off) red[tid] += red[tid + off];
        __syncthreads();
    }
    if (tid == 0) dsh = fmaxf(red[0], 1e-6f);
    __syncthreads();

    float den = dsh;
    float* row = out + OUT_CQ_OFF + n * ROW;
    if (tid < DIM) {
        row[tid] = cqs[tid];
        row[DIM + tid] /= den;
    }
}

extern "C" void kernel_launch(void* const* d_in, const int* in_sizes, int n_in,
                              void* d_out, int out_size, void* d_ws, size_t ws_size,
                              hipStream_t stream)
{
    const float* cq     = (const float*)d_in[0];
    const float* pixels = (const float*)d_in[1];
    const float* ego    = (const float*)d_in[2];
    const float* Ww     = (const float*)d_in[3];
    const float* bw     = (const float*)d_in[4];
    const float* f0     = (const float*)d_in[5];
    const float* f1     = (const float*)d_in[6];
    const float* f2     = (const float*)d_in[7];

    float* out = (float*)d_out;
    bool fast = (d_ws != nullptr) && (ws_size >= WS_NEED);

    if (fast) {
        u16*   tf    = (u16*)d_ws;
        float* wbase = (float*)((char*)d_ws + TF_BYTES);
        init_kernel<<<262, 320, 0, stream>>>(cq, Ww, bw, pixels, wbase, out);
        transpose_kernel<<<20160, 256, 0, stream>>>(f0, f1, f2, tf);
        gather_tr_kernel<<<NQ * SCH, 256, 0, stream>>>(pixels, ego, wbase, tf, out);
    } else {
        copy_zero_kernel<<<134, 256, 0, stream>>>(pixels, out);
        gather_kernel<<<18 * NQ, 256, 0, stream>>>(cq, pixels, ego, Ww, bw,
                                                   f0, f1, f2, out);
    }

    epilogue_kernel<<<NQ, 512, 0, stream>>>(cq, pixels, ego, Ww, bw, out);
}

// Round 8
// 474.502 us; speedup vs baseline: 3.1028x; 1.0331x over previous
//
#include <hip/hip_runtime.h>

#define NQ   128
#define DIM  256
#define WCN  306      // Ncam*P*L
#define NCAM 6
#define PP   17
#define LV   3
#define TT   4
#define PIX_ELEMS 104448          // 4*128*6*17*2 f32 elements (output 0)
#define OUT_CQ_OFF PIX_ELEMS
#define ROW  (2 * DIM)            // 512 f32 per query row: [cq | agg]

// ---- transposed-feature geometry (channel-last bf16 in d_ws) ----
#define SPAT_L0 245760            // 24 planes * 10240
#define SPAT_L1 61440             // 24 * 2560
#define SPAT_L2 15360             // 24 * 640
#define SPAT_TOTAL (SPAT_L0 + SPAT_L1 + SPAT_L2)   // 322560
#define TF_ELEMS ((size_t)SPAT_TOTAL * 256)        // 82,575,360 bf16
#define TF_BYTES (TF_ELEMS * 2)                    // 165,150,720 B
#define WB_BYTES ((size_t)NQ * WCN * 4)            // 156,672 B
#define DEN_BYTES ((size_t)NQ * 4)                 // 512 B
#define WS_NEED  (TF_BYTES + WB_BYTES + DEN_BYTES)

#define SCH 12                    // gather chunks per query
#define RPB 102                   // records per gather block (1224/12)

typedef unsigned short u16;

__device__ __forceinline__ float b2f(u16 u) {
    union { unsigned int i; float f; } v;
    v.i = ((unsigned int)u) << 16;
    return v.f;
}
__device__ __forceinline__ u16 f2b(float f) {
    union { float f; unsigned int i; } v;
    v.f = f;
    unsigned int x = v.i;
    return (u16)((x + 0x7FFFu + ((x >> 16) & 1u)) >> 16);
}
__device__ __forceinline__ void calc_tw(const float* ego, float* tw) {
    float e3 = ego[TT - 1];
    #pragma unroll
    for (int t = 0; t < TT; ++t) {
        float d = ego[t] - e3;
        tw[t] = expf(-d * d * 6.0f);   // exp(-td^2/DECAY*3), DECAY=0.5
    }
}

// ---------------------------------------------------------------------------
// K1 init (merged): blocks 0..127 -> wbase GEMV+sigmoid AND den[n] (round-6:
// den moved here from epilogue, which used to redo the whole GEMV); blocks
// 128..229 -> pixel copy; 230..261 -> zero agg slots. Grid 262 x 320.
// ---------------------------------------------------------------------------
__global__ __launch_bounds__(320) void init_kernel(
    const float* __restrict__ cq, const float* __restrict__ Ww,
    const float* __restrict__ bw, const float* __restrict__ pixels,
    const float* __restrict__ ego,
    float* __restrict__ wbase, float* __restrict__ den,
    float* __restrict__ out)
{
    int bid = blockIdx.x, tid = threadIdx.x;
    if (bid < 128) {
        int n = bid;
        __shared__ float cqs[DIM];
        __shared__ float red[320];
        if (tid < DIM) cqs[tid] = cq[n * DIM + tid];
        __syncthreads();

        float denj = 0.f;
        if (tid < WCN) {
            int j = tid;
            float acc = bw[j];
            #pragma unroll 8
            for (int d = 0; d < DIM; ++d) acc += cqs[d] * Ww[d * WCN + j];
            float sig = 1.0f / (1.0f + expf(-acc));
            wbase[n * WCN + j] = sig;
            // den contribution: sig * sum_t tw[t] * (px0 >= 0)
            float tw[TT]; calc_tw(ego, tw);
            int cam = j / (PP * LV);
            int rem = j - cam * (PP * LV);
            int p   = rem / LV;
            float s = 0.f;
            #pragma unroll
            for (int t = 0; t < TT; ++t) {
                float px0 = pixels[(((t * NQ + n) * NCAM + cam) * PP + p) << 1];
                s += (px0 < 0.f) ? 0.f : tw[t];
            }
            denj = sig * s;
        }
        red[tid] = denj;
        __syncthreads();
        if (tid < 64) red[tid] += red[tid + 256];
        __syncthreads();
        for (int off = 128; off > 0; off >>= 1) {
            if (tid < off) red[tid] += red[tid + off];
            __syncthreads();
        }
        if (tid == 0) den[n] = fmaxf(red[0], 1e-6f);
    } else if (bid < 230) {
        if (tid < 256) {
            int v = (bid - 128) * 256 + tid;
            ((float4*)out)[v] = ((const float4*)pixels)[v];
        }
    } else {
        if (tid < 256) {
            int v = (bid - 230) * 256 + tid;
            int n  = v >> 6;
            int c4 = (v & 63) << 2;
            *(float4*)(out + OUT_CQ_OFF + n * ROW + DIM + c4) =
                make_float4(0.f, 0.f, 0.f, 0.f);
        }
    }
}

// ---------------------------------------------------------------------------
// Kernel T: transpose [cam*t][C][H*W] f32 -> [cam*t][H*W][C] bf16.
// 64x64 tiles via LDS. Grid = 15360 (l0) + 3840 (l1) + 960 (l2) = 20160.
// (Verbatim champion; 2-way LDS bank aliasing only = free.)
// ---------------------------------------------------------------------------
__global__ __launch_bounds__(256) void transpose_kernel(
    const float* __restrict__ f0, const float* __restrict__ f1,
    const float* __restrict__ f2, u16* __restrict__ tf)
{
    __shared__ float lds[64][65];   // [hw_local][c_local], pad 65
    int bid = blockIdx.x, tid = threadIdx.x;
    int plane, ctile, hwtile, HW, spat_base;
    const float* src;
    if (bid < 15360) {
        HW = 10240; src = f0; spat_base = 0;
        plane = bid / 640; int r = bid - plane * 640; ctile = r / 160; hwtile = r - ctile * 160;
    } else if (bid < 19200) {
        int b = bid - 15360; HW = 2560; src = f1; spat_base = SPAT_L0;
        plane = b / 160; int r = b - plane * 160; ctile = r / 40; hwtile = r - ctile * 40;
    } else {
        int b = bid - 19200; HW = 640; src = f2; spat_base = SPAT_L0 + SPAT_L1;
        plane = b / 40; int r = b - plane * 40; ctile = r / 10; hwtile = r - ctile * 10;
    }
    int hw0 = hwtile * 64;
    int c0  = ctile * 64;

    // read: coalesced float4 along hw; thread (cl = tid/16, hl = (tid%16)*4)
    const float* sp = src + ((size_t)plane * 256 + c0) * HW + hw0;
    int cl = tid >> 4;
    int hl = (tid & 15) << 2;
    #pragma unroll
    for (int pass = 0; pass < 4; ++pass) {
        int c = pass * 16 + cl;
        float4 v = *(const float4*)(sp + (size_t)c * HW + hl);
        lds[hl + 0][c] = v.x; lds[hl + 1][c] = v.y;
        lds[hl + 2][c] = v.z; lds[hl + 3][c] = v.w;
    }
    __syncthreads();

    // write: coalesced ushort4 along c; thread (hr = tid/16, c4 = (tid%16)*4)
    int hr = tid >> 4;
    int c4 = (tid & 15) << 2;
    u16* dp = tf + ((size_t)(spat_base + plane * HW + hw0)) * 256 + c0;
    #pragma unroll
    for (int pass = 0; pass < 4; ++pass) {
        int hw = pass * 16 + hr;
        ushort4 o = make_ushort4(f2b(lds[hw][c4 + 0]), f2b(lds[hw][c4 + 1]),
                                 f2b(lds[hw][c4 + 2]), f2b(lds[hw][c4 + 3]));
        *(ushort4*)(dp + (size_t)hw * 256 + c4) = o;
    }
}

// ---------------------------------------------------------------------------
// Kernel G: coalesced gather from channel-last bf16 features.
// Grid = NQ * SCH blocks; 256 threads = 4 waves. Manual 2-record software
// pipeline — issue record (i+4)'s 4 corner loads BEFORE the FMAs of record
// i, doubling loads-in-flight per wave (latency-hiding probe: if gather is
// latency-bound this is -25..45us; if BW-bound, ~0 — either is informative).
// ---------------------------------------------------------------------------
__global__ __launch_bounds__(256) void gather_tr_kernel(
    const float* __restrict__ pixels, const float* __restrict__ ego,
    const float* __restrict__ wbase, const u16* __restrict__ tf,
    float* __restrict__ out)
{
    int bid = blockIdx.x;
    int n = bid / SCH;
    int chunk = bid - n * SCH;
    int tid = threadIdx.x;

    __shared__ int   offs[RPB][4];
    __shared__ float wts[RPB][4];
    __shared__ float red[4][DIM];

    if (tid < RPB) {
        int r = chunk * RPB + tid;
        int t = r / WCN;  int j = r - t * WCN;
        int cam = j / 51; int rem = j - cam * 51;
        int p = rem / 3;  int l = rem - p * 3;
        float e3 = ego[TT - 1];
        float dt = ego[t] - e3;
        float tw = expf(-dt * dt * 6.0f);
        int pidx = (((t * NQ + n) * NCAM + cam) * PP + p) << 1;
        float px0 = pixels[pidx], px1 = pixels[pidx + 1];
        float w = wbase[n * WCN + j] * tw;
        if (px0 < 0.f) w = 0.f;
        int W_ = (l == 0) ? 160 : ((l == 1) ? 80 : 40);
        int H_ = (l == 0) ? 64  : ((l == 1) ? 32 : 16);
        int HW = W_ * H_;
        int sb = (l == 0) ? 0 : ((l == 1) ? SPAT_L0 : (SPAT_L0 + SPAT_L1));
        float ix = px0 * (float)(W_ - 1);     // == (gx+1)/2*(W-1)
        float iy = px1 * (float)(H_ - 1);
        float x0f = floorf(ix), y0f = floorf(iy);
        float wx1 = ix - x0f, wy1 = iy - y0f;
        float wx0 = 1.f - wx1, wy0 = 1.f - wy1;
        int x0 = (int)x0f, y0 = (int)y0f;
        int x1 = x0 + 1,  y1 = y0 + 1;
        bool vx0 = (x0 >= 0) & (x0 < W_), vx1 = (x1 >= 0) & (x1 < W_);
        bool vy0 = (y0 >= 0) & (y0 < H_), vy1 = (y1 >= 0) & (y1 < H_);
        int cx0 = min(max(x0, 0), W_ - 1), cx1 = min(max(x1, 0), W_ - 1);
        int cy0 = min(max(y0, 0), H_ - 1), cy1 = min(max(y1, 0), H_ - 1);
        int base = sb + (cam * TT + t) * HW;
        offs[tid][0] = base + cy0 * W_ + cx0;
        offs[tid][1] = base + cy0 * W_ + cx1;
        offs[tid][2] = base + cy1 * W_ + cx0;
        offs[tid][3] = base + cy1 * W_ + cx1;
        wts[tid][0] = w * wy0 * wx0 * ((vx0 & vy0) ? 1.f : 0.f);
        wts[tid][1] = w * wy0 * wx1 * ((vx1 & vy0) ? 1.f : 0.f);
        wts[tid][2] = w * wy1 * wx0 * ((vx0 & vy1) ? 1.f : 0.f);
        wts[tid][3] = w * wy1 * wx1 * ((vx1 & vy1) ? 1.f : 0.f);
    }
    __syncthreads();

    int wv   = tid >> 6;
    int lane = tid & 63;
    float acc0 = 0.f, acc1 = 0.f, acc2 = 0.f, acc3 = 0.f;

    const u16* tfl = tf + (lane << 2);   // per-lane channel base

    // software pipeline: record i in flight while record i+4 is issued
    int i = wv;                          // wave-uniform
    float w0[4]; ushort4 v0[4];
    #pragma unroll
    for (int q = 0; q < 4; ++q) {
        w0[q] = wts[i][q];
        v0[q] = *(const ushort4*)(tfl + (size_t)offs[i][q] * 256);
    }
    while (true) {
        int inext = i + 4;
        bool have_next = (inext < RPB);  // wave-uniform branch
        float w1[4]; ushort4 v1[4];
        if (have_next) {
            #pragma unroll
            for (int q = 0; q < 4; ++q) {
                w1[q] = wts[inext][q];
                v1[q] = *(const ushort4*)(tfl + (size_t)offs[inext][q] * 256);
            }
        }
        #pragma unroll
        for (int q = 0; q < 4; ++q) {
            float wq = w0[q];
            acc0 += wq * b2f(v0[q].x);
            acc1 += wq * b2f(v0[q].y);
            acc2 += wq * b2f(v0[q].z);
            acc3 += wq * b2f(v0[q].w);
        }
        if (!have_next) break;
        i = inext;
        #pragma unroll
        for (int q = 0; q < 4; ++q) { w0[q] = w1[q]; v0[q] = v1[q]; }
    }

    int cb = lane << 2;
    red[wv][cb + 0] = acc0; red[wv][cb + 1] = acc1;
    red[wv][cb + 2] = acc2; red[wv][cb + 3] = acc3;
    __syncthreads();
    if (tid < DIM) {
        float s = red[0][tid] + red[1][tid] + red[2][tid] + red[3][tid];
        atomicAdd(&out[OUT_CQ_OFF + n * ROW + DIM + tid], s);
    }
}

// ---------------------------------------------------------------------------
// K4 fast epilogue: pure divide + cq copy (den precomputed in init).
// Grid NQ x 256.
// ---------------------------------------------------------------------------
__global__ __launch_bounds__(256) void epilogue_fast_kernel(
    const float* __restrict__ cq, const float* __restrict__ den,
    float* __restrict__ out)
{
    int n = blockIdx.x, tid = threadIdx.x;
    float d = den[n];
    float* row = out + OUT_CQ_OFF + n * ROW;
    row[tid] = cq[n * DIM + tid];
    row[DIM + tid] /= d;
}

// ---------------------------------------------------------------------------
// Fallback path (tiny ws): copy/zero + channel-major direct gather +
// self-contained epilogue (recomputes den).
// ---------------------------------------------------------------------------
__global__ __launch_bounds__(256) void copy_zero_kernel(
    const float* __restrict__ pixels, float* __restrict__ out)
{
    int bid = blockIdx.x, tid = threadIdx.x;
    if (bid < 102) {
        int v = bid * 256 + tid;
        ((float4*)out)[v] = ((const float4*)pixels)[v];
    } else {
        int v = (bid - 102) * 256 + tid;
        int n  = v >> 6;
        int c4 = (v & 63) << 2;
        float4* dst = (float4*)(out + OUT_CQ_OFF + n * ROW + DIM + c4);
        *dst = make_float4(0.f, 0.f, 0.f, 0.f);
    }
}

__global__ __launch_bounds__(256) void gather_kernel(
    const float* __restrict__ cq, const float* __restrict__ pixels,
    const float* __restrict__ ego, const float* __restrict__ Ww,
    const float* __restrict__ bw,
    const float* __restrict__ f0, const float* __restrict__ f1,
    const float* __restrict__ f2, float* __restrict__ out)
{
    int bid = blockIdx.x;
    int n   = bid & (NQ - 1);
    int g   = bid >> 7;
    int l   = g / NCAM;
    int cam = g - l * NCAM;
    int tid = threadIdx.x;

    __shared__ float cqs[DIM];
    __shared__ float ws[PP];
    __shared__ float pix[TT * PP * 2];
    __shared__ int4   offs4[TT * PP];
    __shared__ float4 wt4[TT * PP];

    cqs[tid] = cq[n * DIM + tid];
    if (tid < TT * PP * 2) {
        int t = tid / (PP * 2);
        int r = tid - t * (PP * 2);
        int p = r >> 1, comp = r & 1;
        pix[tid] = pixels[((((t * NQ + n) * NCAM + cam) * PP + p) << 1) + comp];
    }
    __syncthreads();

    if (tid < PP) {
        int j = cam * (PP * LV) + tid * LV + l;
        float acc = bw[j];
        #pragma unroll 8
        for (int d = 0; d < DIM; ++d) acc += cqs[d] * Ww[d * WCN + j];
        ws[tid] = 1.0f / (1.0f + expf(-acc));
    }
    __syncthreads();

    const int W_ = (l == 0) ? 160 : ((l == 1) ? 80 : 40);
    const int H_ = (l == 0) ? 64  : ((l == 1) ? 32 : 16);
    const int HW = W_ * H_;

    if (tid < TT * PP) {
        int t = tid / PP, p = tid - t * PP;
        float twl[TT]; calc_tw(ego, twl);
        float px0 = pix[(t * PP + p) * 2];
        float px1 = pix[(t * PP + p) * 2 + 1];
        float w = ws[p] * twl[t];
        if (px0 < 0.f) w = 0.f;
        float ix = px0 * (float)(W_ - 1);
        float iy = px1 * (float)(H_ - 1);
        float x0f = floorf(ix), y0f = floorf(iy);
        float wx1 = ix - x0f, wy1 = iy - y0f;
        float wx0 = 1.f - wx1, wy0 = 1.f - wy1;
        int x0 = (int)x0f, y0 = (int)y0f;
        int x1 = x0 + 1,  y1 = y0 + 1;
        bool vx0 = (x0 >= 0) & (x0 < W_), vx1 = (x1 >= 0) & (x1 < W_);
        bool vy0 = (y0 >= 0) & (y0 < H_), vy1 = (y1 >= 0) & (y1 < H_);
        int cx0 = min(max(x0, 0), W_ - 1), cx1 = min(max(x1, 0), W_ - 1);
        int cy0 = min(max(y0, 0), H_ - 1), cy1 = min(max(y1, 0), H_ - 1);
        offs4[tid] = make_int4(cy0 * W_ + cx0, cy0 * W_ + cx1,
                               cy1 * W_ + cx0, cy1 * W_ + cx1);
        wt4[tid] = make_float4(w * wy0 * wx0 * ((vx0 & vy0) ? 1.f : 0.f),
                               w * wy0 * wx1 * ((vx1 & vy0) ? 1.f : 0.f),
                               w * wy1 * wx0 * ((vx0 & vy1) ? 1.f : 0.f),
                               w * wy1 * wx1 * ((vx1 & vy1) ? 1.f : 0.f));
    }
    __syncthreads();

    const float* fbase = (l == 0) ? f0 : ((l == 1) ? f1 : f2);
    const float* base_c = fbase + (size_t)(cam * TT * DIM + tid) * (size_t)HW;

    float acc = 0.f;
    #pragma unroll
    for (int t = 0; t < TT; ++t) {
        const float* base = base_c + (size_t)t * (size_t)(DIM * HW);
        #pragma unroll 4
        for (int p = 0; p < PP; ++p) {
            int rr = t * PP + p;
            int4 o = offs4[rr];
            float4 w4 = wt4[rr];
            acc += w4.x * base[o.x] + w4.y * base[o.y]
                 + w4.z * base[o.z] + w4.w * base[o.w];
        }
    }
    atomicAdd(&out[OUT_CQ_OFF + n * ROW + DIM + tid], acc);
}

__global__ __launch_bounds__(512) void epilogue_kernel(
    const float* __restrict__ cq, const float* __restrict__ pixels,
    const float* __restrict__ ego, const float* __restrict__ Ww,
    const float* __restrict__ bw, float* __restrict__ out)
{
    int n = blockIdx.x, tid = threadIdx.x;
    __shared__ float cqs[DIM];
    __shared__ float red[512];
    __shared__ float dsh;

    if (tid < DIM) cqs[tid] = cq[n * DIM + tid];
    __syncthreads();

    float tw[TT]; calc_tw(ego, tw);

    float denj = 0.f;
    if (tid < WCN) {
        int j = tid;
        float acc = bw[j];
        #pragma unroll 8
        for (int d = 0; d < DIM; ++d) acc += cqs[d] * Ww[d * WCN + j];
        float sig = 1.0f / (1.0f + expf(-acc));
        int cam = j / (PP * LV);
        int rem = j - cam * (PP * LV);
        int p   = rem / LV;
        float s = 0.f;
        #pragma unroll
        for (int t = 0; t < TT; ++t) {
            float px0 = pixels[(((t * NQ + n) * NCAM + cam) * PP + p) << 1];
            s += (px0 < 0.f) ? 0.f : tw[t];
        }
        denj = sig * s;
    }
    red[tid] = denj;
    __syncthreads();
    for (int off = 256; off > 0; off >>= 1) {
        if (tid < off) red[tid] += red[tid + off];
        __syncthreads();
    }
    if (tid == 0) dsh = fmaxf(red[0], 1e-6f);
    __syncthreads();

    float den = dsh;
    float* row = out + OUT_CQ_OFF + n * ROW;
    if (tid < DIM) {
        row[tid] = cqs[tid];
        row[DIM + tid] /= den;
    }
}

extern "C" void kernel_launch(void* const* d_in, const int* in_sizes, int n_in,
                              void* d_out, int out_size, void* d_ws, size_t ws_size,
                              hipStream_t stream)
{
    const float* cq     = (const float*)d_in[0];
    const float* pixels = (const float*)d_in[1];
    const float* ego    = (const float*)d_in[2];
    const float* Ww     = (const float*)d_in[3];
    const float* bw     = (const float*)d_in[4];
    const float* f0     = (const float*)d_in[5];
    const float* f1     = (const float*)d_in[6];
    const float* f2     = (const float*)d_in[7];

    float* out = (float*)d_out;
    bool fast = (d_ws != nullptr) && (ws_size >= WS_NEED);

    if (fast) {
        u16*   tf    = (u16*)d_ws;
        float* wbase = (float*)((char*)d_ws + TF_BYTES);
        float* den   = (float*)((char*)d_ws + TF_BYTES + WB_BYTES);
        init_kernel<<<262, 320, 0, stream>>>(cq, Ww, bw, pixels, ego,
                                             wbase, den, out);
        transpose_kernel<<<20160, 256, 0, stream>>>(f0, f1, f2, tf);
        gather_tr_kernel<<<NQ * SCH, 256, 0, stream>>>(pixels, ego, wbase, tf, out);
        epilogue_fast_kernel<<<NQ, 256, 0, stream>>>(cq, den, out);
    } else {
        copy_zero_kernel<<<134, 256, 0, stream>>>(pixels, out);
        gather_kernel<<<18 * NQ, 256, 0, stream>>>(cq, pixels, ego, Ww, bw,
                                                   f0, f1, f2, out);
        epilogue_kernel<<<NQ, 512, 0, stream>>>(cq, pixels, ego, Ww, bw, out);
    }
}

// Round 9
// 451.418 us; speedup vs baseline: 3.2615x; 1.0511x over previous
//
#include <hip/hip_runtime.h>

#define NQ   128
#define DIM  256
#define WCN  306      // Ncam*P*L
#define NCAM 6
#define PP   17
#define LV   3
#define TT   4
#define PIX_ELEMS 104448          // 4*128*6*17*2 f32 elements (output 0)
#define OUT_CQ_OFF PIX_ELEMS
#define ROW  (2 * DIM)            // 512 f32 per query row: [cq | agg]

// ---- transposed-feature geometry (channel-last bf16 in d_ws) ----
#define SPAT_L0 245760            // 24 planes * 10240
#define SPAT_L1 61440             // 24 * 2560
#define SPAT_L2 15360             // 24 * 640
#define SPAT_TOTAL (SPAT_L0 + SPAT_L1 + SPAT_L2)   // 322560
#define TF_ELEMS ((size_t)SPAT_TOTAL * 256)        // 82,575,360 bf16
#define TF_BYTES (TF_ELEMS * 2)                    // 165,150,720 B
#define WB_BYTES ((size_t)NQ * WCN * 4)            // 156,672 B
#define DEN_BYTES ((size_t)NQ * 4)                 // 512 B
#define WS_NEED  (TF_BYTES + WB_BYTES + DEN_BYTES)

#define SCH 12                    // gather chunks per query
#define RPB 102                   // records per gather block (1224/12)

typedef unsigned short u16;

__device__ __forceinline__ float b2f(u16 u) {
    union { unsigned int i; float f; } v;
    v.i = ((unsigned int)u) << 16;
    return v.f;
}
__device__ __forceinline__ u16 f2b(float f) {
    union { float f; unsigned int i; } v;
    v.f = f;
    unsigned int x = v.i;
    return (u16)((x + 0x7FFFu + ((x >> 16) & 1u)) >> 16);
}
__device__ __forceinline__ void calc_tw(const float* ego, float* tw) {
    float e3 = ego[TT - 1];
    #pragma unroll
    for (int t = 0; t < TT; ++t) {
        float d = ego[t] - e3;
        tw[t] = expf(-d * d * 6.0f);   // exp(-td^2/DECAY*3), DECAY=0.5
    }
}

// ---------------------------------------------------------------------------
// K1 prep (round-9 merge of init + transpose into ONE launch, 256 thr):
//   blocks 0..127    : wbase GEMV+sigmoid + den[n] (j = tid and tid+256)
//   blocks 128..229  : pixel copy
//   blocks 230..261  : zero agg slots
//   blocks 262..20421: 64x64 transpose tiles (bid-262), champion layout
// ---------------------------------------------------------------------------
__global__ __launch_bounds__(256) void prep_kernel(
    const float* __restrict__ cq, const float* __restrict__ Ww,
    const float* __restrict__ bw, const float* __restrict__ pixels,
    const float* __restrict__ ego,
    const float* __restrict__ f0, const float* __restrict__ f1,
    const float* __restrict__ f2,
    float* __restrict__ wbase, float* __restrict__ den,
    u16* __restrict__ tf, float* __restrict__ out)
{
    int bid = blockIdx.x, tid = threadIdx.x;

    if (bid < 128) {
        int n = bid;
        __shared__ float cqs[DIM];
        __shared__ float redl[256];
        cqs[tid] = cq[n * DIM + tid];
        __syncthreads();

        float tw[TT]; calc_tw(ego, tw);
        float denj = 0.f;
        {
            int j = tid;
            float acc = bw[j];
            #pragma unroll 8
            for (int d = 0; d < DIM; ++d) acc += cqs[d] * Ww[d * WCN + j];
            float sig = 1.0f / (1.0f + expf(-acc));
            wbase[n * WCN + j] = sig;
            int cam = j / (PP * LV);
            int rem = j - cam * (PP * LV);
            int p   = rem / LV;
            float s = 0.f;
            #pragma unroll
            for (int t = 0; t < TT; ++t) {
                float px0 = pixels[(((t * NQ + n) * NCAM + cam) * PP + p) << 1];
                s += (px0 < 0.f) ? 0.f : tw[t];
            }
            denj = sig * s;
        }
        if (tid < WCN - 256) {           // j = 256..305
            int j = tid + 256;
            float acc = bw[j];
            #pragma unroll 8
            for (int d = 0; d < DIM; ++d) acc += cqs[d] * Ww[d * WCN + j];
            float sig = 1.0f / (1.0f + expf(-acc));
            wbase[n * WCN + j] = sig;
            int cam = j / (PP * LV);
            int rem = j - cam * (PP * LV);
            int p   = rem / LV;
            float s = 0.f;
            #pragma unroll
            for (int t = 0; t < TT; ++t) {
                float px0 = pixels[(((t * NQ + n) * NCAM + cam) * PP + p) << 1];
                s += (px0 < 0.f) ? 0.f : tw[t];
            }
            denj += sig * s;
        }
        redl[tid] = denj;
        __syncthreads();
        for (int off = 128; off > 0; off >>= 1) {
            if (tid < off) redl[tid] += redl[tid + off];
            __syncthreads();
        }
        if (tid == 0) den[n] = fmaxf(redl[0], 1e-6f);
        return;
    }
    if (bid < 230) {
        int v = (bid - 128) * 256 + tid;
        ((float4*)out)[v] = ((const float4*)pixels)[v];
        return;
    }
    if (bid < 262) {
        int v = (bid - 230) * 256 + tid;
        int n  = v >> 6;
        int c4 = (v & 63) << 2;
        *(float4*)(out + OUT_CQ_OFF + n * ROW + DIM + c4) =
            make_float4(0.f, 0.f, 0.f, 0.f);
        return;
    }

    // ---- transpose tile ----
    int b = bid - 262;
    __shared__ float lds[64][65];   // [hw_local][c_local], pad 65
    int plane, ctile, hwtile, HW, spat_base;
    const float* src;
    if (b < 15360) {
        HW = 10240; src = f0; spat_base = 0;
        plane = b / 640; int r = b - plane * 640; ctile = r / 160; hwtile = r - ctile * 160;
    } else if (b < 19200) {
        int b1 = b - 15360; HW = 2560; src = f1; spat_base = SPAT_L0;
        plane = b1 / 160; int r = b1 - plane * 160; ctile = r / 40; hwtile = r - ctile * 40;
    } else {
        int b1 = b - 19200; HW = 640; src = f2; spat_base = SPAT_L0 + SPAT_L1;
        plane = b1 / 40; int r = b1 - plane * 40; ctile = r / 10; hwtile = r - ctile * 10;
    }
    int hw0 = hwtile * 64;
    int c0  = ctile * 64;

    const float* sp = src + ((size_t)plane * 256 + c0) * HW + hw0;
    int cl = tid >> 4;
    int hl = (tid & 15) << 2;
    #pragma unroll
    for (int pass = 0; pass < 4; ++pass) {
        int c = pass * 16 + cl;
        float4 v = *(const float4*)(sp + (size_t)c * HW + hl);
        lds[hl + 0][c] = v.x; lds[hl + 1][c] = v.y;
        lds[hl + 2][c] = v.z; lds[hl + 3][c] = v.w;
    }
    __syncthreads();

    int hr = tid >> 4;
    int c4 = (tid & 15) << 2;
    u16* dp = tf + ((size_t)(spat_base + plane * HW + hw0)) * 256 + c0;
    #pragma unroll
    for (int pass = 0; pass < 4; ++pass) {
        int hw = pass * 16 + hr;
        ushort4 o = make_ushort4(f2b(lds[hw][c4 + 0]), f2b(lds[hw][c4 + 1]),
                                 f2b(lds[hw][c4 + 2]), f2b(lds[hw][c4 + 3]));
        *(ushort4*)(dp + (size_t)hw * 256 + c4) = o;
    }
}

// ---------------------------------------------------------------------------
// Kernel G (round-9 pair-load): corners (y0,x0)/(y0,x1) are ADJACENT in
// channel-last layout (x1=x0+1; px in [0,1) so never clamped, and a clamped
// corner has weight exactly 0 while the +512B over-read stays inside ws).
// Per record: 2 x 1024B wave transactions (uint4 = 16B/lane); lanes 0..31
// take corner A (channels lc*8..+7), lanes 32..63 corner B. 8-ch register
// acc; red[8][256] merges the half-wave partials. 2-deep pipeline retained.
// ---------------------------------------------------------------------------
__global__ __launch_bounds__(256) void gather_tr_kernel(
    const float* __restrict__ pixels, const float* __restrict__ ego,
    const float* __restrict__ wbase, const u16* __restrict__ tf,
    float* __restrict__ out)
{
    int bid = blockIdx.x;
    int n = bid / SCH;
    int chunk = bid - n * SCH;
    int tid = threadIdx.x;

    __shared__ int   offs[RPB][2];    // corner-pair bases: (y0 row, y1 row)
    __shared__ float wts[RPB][4];
    __shared__ float red[8][DIM];

    if (tid < RPB) {
        int r = chunk * RPB + tid;
        int t = r / WCN;  int j = r - t * WCN;
        int cam = j / 51; int rem = j - cam * 51;
        int p = rem / 3;  int l = rem - p * 3;
        float e3 = ego[TT - 1];
        float dt = ego[t] - e3;
        float tw = expf(-dt * dt * 6.0f);
        int pidx = (((t * NQ + n) * NCAM + cam) * PP + p) << 1;
        float px0 = pixels[pidx], px1 = pixels[pidx + 1];
        float w = wbase[n * WCN + j] * tw;
        if (px0 < 0.f) w = 0.f;
        int W_ = (l == 0) ? 160 : ((l == 1) ? 80 : 40);
        int H_ = (l == 0) ? 64  : ((l == 1) ? 32 : 16);
        int HW = W_ * H_;
        int sb = (l == 0) ? 0 : ((l == 1) ? SPAT_L0 : (SPAT_L0 + SPAT_L1));
        float ix = px0 * (float)(W_ - 1);     // == (gx+1)/2*(W-1)
        float iy = px1 * (float)(H_ - 1);
        float x0f = floorf(ix), y0f = floorf(iy);
        float wx1 = ix - x0f, wy1 = iy - y0f;
        float wx0 = 1.f - wx1, wy0 = 1.f - wy1;
        int x0 = (int)x0f, y0 = (int)y0f;
        int x1 = x0 + 1,  y1 = y0 + 1;
        bool vx0 = (x0 >= 0) & (x0 < W_), vx1 = (x1 >= 0) & (x1 < W_);
        bool vy0 = (y0 >= 0) & (y0 < H_), vy1 = (y1 >= 0) & (y1 < H_);
        int cx0 = min(max(x0, 0), W_ - 1);
        int cy0 = min(max(y0, 0), H_ - 1), cy1 = min(max(y1, 0), H_ - 1);
        int base = sb + (cam * TT + t) * HW;
        offs[tid][0] = base + cy0 * W_ + cx0;   // pair covers +0 (x0), +1 (x1)
        offs[tid][1] = base + cy1 * W_ + cx0;
        wts[tid][0] = w * wy0 * wx0 * ((vx0 & vy0) ? 1.f : 0.f);
        wts[tid][1] = w * wy0 * wx1 * ((vx1 & vy0) ? 1.f : 0.f);
        wts[tid][2] = w * wy1 * wx0 * ((vx0 & vy1) ? 1.f : 0.f);
        wts[tid][3] = w * wy1 * wx1 * ((vx1 & vy1) ? 1.f : 0.f);
    }
    __syncthreads();

    int wv   = tid >> 6;
    int lane = tid & 63;
    int half = lane >> 5;           // 0: corner x0, 1: corner x1
    int lc   = lane & 31;           // channel group: lc*8 .. lc*8+7
    float acc[8];
    #pragma unroll
    for (int k = 0; k < 8; ++k) acc[k] = 0.f;

    const u16* tfh = tf + half * 256 + lc * 8;

    // 2-deep software pipeline over records i = wv, wv+4, ...
    int i = wv;
    int   o0 = offs[i][0], o1 = offs[i][1];
    float wA = wts[i][half], wB = wts[i][2 + half];
    uint4 A = *(const uint4*)(tfh + (size_t)o0 * 256);
    uint4 B = *(const uint4*)(tfh + (size_t)o1 * 256);
    while (true) {
        int inext = i + 4;
        bool have_next = (inext < RPB);   // wave-uniform
        uint4 A1, B1; float wA1 = 0.f, wB1 = 0.f;
        if (have_next) {
            int o0n = offs[inext][0], o1n = offs[inext][1];
            wA1 = wts[inext][half]; wB1 = wts[inext][2 + half];
            A1 = *(const uint4*)(tfh + (size_t)o0n * 256);
            B1 = *(const uint4*)(tfh + (size_t)o1n * 256);
        }
        unsigned ua[4] = {A.x, A.y, A.z, A.w};
        unsigned ub[4] = {B.x, B.y, B.z, B.w};
        #pragma unroll
        for (int k = 0; k < 4; ++k) {
            acc[2 * k]     += wA * b2f((u16)(ua[k] & 0xFFFFu))
                            + wB * b2f((u16)(ub[k] & 0xFFFFu));
            acc[2 * k + 1] += wA * b2f((u16)(ua[k] >> 16))
                            + wB * b2f((u16)(ub[k] >> 16));
        }
        if (!have_next) break;
        i = inext;
        A = A1; B = B1; wA = wA1; wB = wB1;
    }

    int row = wv * 2 + half;
    int cb = lc * 8;
    #pragma unroll
    for (int k = 0; k < 8; ++k) red[row][cb + k] = acc[k];
    __syncthreads();
    if (tid < DIM) {
        float s = 0.f;
        #pragma unroll
        for (int r = 0; r < 8; ++r) s += red[r][tid];
        atomicAdd(&out[OUT_CQ_OFF + n * ROW + DIM + tid], s);
    }
}

// ---------------------------------------------------------------------------
// K4 fast epilogue: pure divide + cq copy (den precomputed in prep).
// ---------------------------------------------------------------------------
__global__ __launch_bounds__(256) void epilogue_fast_kernel(
    const float* __restrict__ cq, const float* __restrict__ den,
    float* __restrict__ out)
{
    int n = blockIdx.x, tid = threadIdx.x;
    float d = den[n];
    float* row = out + OUT_CQ_OFF + n * ROW;
    row[tid] = cq[n * DIM + tid];
    row[DIM + tid] /= d;
}

// ---------------------------------------------------------------------------
// Fallback path (tiny ws): copy/zero + channel-major direct gather +
// self-contained epilogue (recomputes den).
// ---------------------------------------------------------------------------
__global__ __launch_bounds__(256) void copy_zero_kernel(
    const float* __restrict__ pixels, float* __restrict__ out)
{
    int bid = blockIdx.x, tid = threadIdx.x;
    if (bid < 102) {
        int v = bid * 256 + tid;
        ((float4*)out)[v] = ((const float4*)pixels)[v];
    } else {
        int v = (bid - 102) * 256 + tid;
        int n  = v >> 6;
        int c4 = (v & 63) << 2;
        float4* dst = (float4*)(out + OUT_CQ_OFF + n * ROW + DIM + c4);
        *dst = make_float4(0.f, 0.f, 0.f, 0.f);
    }
}

__global__ __launch_bounds__(256) void gather_kernel(
    const float* __restrict__ cq, const float* __restrict__ pixels,
    const float* __restrict__ ego, const float* __restrict__ Ww,
    const float* __restrict__ bw,
    const float* __restrict__ f0, const float* __restrict__ f1,
    const float* __restrict__ f2, float* __restrict__ out)
{
    int bid = blockIdx.x;
    int n   = bid & (NQ - 1);
    int g   = bid >> 7;
    int l   = g / NCAM;
    int cam = g - l * NCAM;
    int tid = threadIdx.x;

    __shared__ float cqs[DIM];
    __shared__ float ws[PP];
    __shared__ float pix[TT * PP * 2];
    __shared__ int4   offs4[TT * PP];
    __shared__ float4 wt4[TT * PP];

    cqs[tid] = cq[n * DIM + tid];
    if (tid < TT * PP * 2) {
        int t = tid / (PP * 2);
        int r = tid - t * (PP * 2);
        int p = r >> 1, comp = r & 1;
        pix[tid] = pixels[((((t * NQ + n) * NCAM + cam) * PP + p) << 1) + comp];
    }
    __syncthreads();

    if (tid < PP) {
        int j = cam * (PP * LV) + tid * LV + l;
        float acc = bw[j];
        #pragma unroll 8
        for (int d = 0; d < DIM; ++d) acc += cqs[d] * Ww[d * WCN + j];
        ws[tid] = 1.0f / (1.0f + expf(-acc));
    }
    __syncthreads();

    const int W_ = (l == 0) ? 160 : ((l == 1) ? 80 : 40);
    const int H_ = (l == 0) ? 64  : ((l == 1) ? 32 : 16);
    const int HW = W_ * H_;

    if (tid < TT * PP) {
        int t = tid / PP, p = tid - t * PP;
        float twl[TT]; calc_tw(ego, twl);
        float px0 = pix[(t * PP + p) * 2];
        float px1 = pix[(t * PP + p) * 2 + 1];
        float w = ws[p] * twl[t];
        if (px0 < 0.f) w = 0.f;
        float ix = px0 * (float)(W_ - 1);
        float iy = px1 * (float)(H_ - 1);
        float x0f = floorf(ix), y0f = floorf(iy);
        float wx1 = ix - x0f, wy1 = iy - y0f;
        float wx0 = 1.f - wx1, wy0 = 1.f - wy1;
        int x0 = (int)x0f, y0 = (int)y0f;
        int x1 = x0 + 1,  y1 = y0 + 1;
        bool vx0 = (x0 >= 0) & (x0 < W_), vx1 = (x1 >= 0) & (x1 < W_);
        bool vy0 = (y0 >= 0) & (y0 < H_), vy1 = (y1 >= 0) & (y1 < H_);
        int cx0 = min(max(x0, 0), W_ - 1), cx1 = min(max(x1, 0), W_ - 1);
        int cy0 = min(max(y0, 0), H_ - 1), cy1 = min(max(y1, 0), H_ - 1);
        offs4[tid] = make_int4(cy0 * W_ + cx0, cy0 * W_ + cx1,
                               cy1 * W_ + cx0, cy1 * W_ + cx1);
        wt4[tid] = make_float4(w * wy0 * wx0 * ((vx0 & vy0) ? 1.f : 0.f),
                               w * wy0 * wx1 * ((vx1 & vy0) ? 1.f : 0.f),
                               w * wy1 * wx0 * ((vx0 & vy1) ? 1.f : 0.f),
                               w * wy1 * wx1 * ((vx1 & vy1) ? 1.f : 0.f));
    }
    __syncthreads();

    const float* fbase = (l == 0) ? f0 : ((l == 1) ? f1 : f2);
    const float* base_c = fbase + (size_t)(cam * TT * DIM + tid) * (size_t)HW;

    float acc = 0.f;
    #pragma unroll
    for (int t = 0; t < TT; ++t) {
        const float* base = base_c + (size_t)t * (size_t)(DIM * HW);
        #pragma unroll 4
        for (int p = 0; p < PP; ++p) {
            int rr = t * PP + p;
            int4 o = offs4[rr];
            float4 w4 = wt4[rr];
            acc += w4.x * base[o.x] + w4.y * base[o.y]
                 + w4.z * base[o.z] + w4.w * base[o.w];
        }
    }
    atomicAdd(&out[OUT_CQ_OFF + n * ROW + DIM + tid], acc);
}

__global__ __launch_bounds__(512) void epilogue_kernel(
    const float* __restrict__ cq, const float* __restrict__ pixels,
    const float* __restrict__ ego, const float* __restrict__ Ww,
    const float* __restrict__ bw, float* __restrict__ out)
{
    int n = blockIdx.x, tid = threadIdx.x;
    __shared__ float cqs[DIM];
    __shared__ float red[512];
    __shared__ float dsh;

    if (tid < DIM) cqs[tid] = cq[n * DIM + tid];
    __syncthreads();

    float tw[TT]; calc_tw(ego, tw);

    float denj = 0.f;
    if (tid < WCN) {
        int j = tid;
        float acc = bw[j];
        #pragma unroll 8
        for (int d = 0; d < DIM; ++d) acc += cqs[d] * Ww[d * WCN + j];
        float sig = 1.0f / (1.0f + expf(-acc));
        int cam = j / (PP * LV);
        int rem = j - cam * (PP * LV);
        int p   = rem / LV;
        float s = 0.f;
        #pragma unroll
        for (int t = 0; t < TT; ++t) {
            float px0 = pixels[(((t * NQ + n) * NCAM + cam) * PP + p) << 1];
            s += (px0 < 0.f) ? 0.f : tw[t];
        }
        denj = sig * s;
    }
    red[tid] = denj;
    __syncthreads();
    for (int off = 256; off > 0; off >>= 1) {
        if (tid < off) red[tid] += red[tid + off];
        __syncthreads();
    }
    if (tid == 0) dsh = fmaxf(red[0], 1e-6f);
    __syncthreads();

    float den = dsh;
    float* row = out + OUT_CQ_OFF + n * ROW;
    if (tid < DIM) {
        row[tid] = cqs[tid];
        row[DIM + tid] /= den;
    }
}

extern "C" void kernel_launch(void* const* d_in, const int* in_sizes, int n_in,
                              void* d_out, int out_size, void* d_ws, size_t ws_size,
                              hipStream_t stream)
{
    const float* cq     = (const float*)d_in[0];
    const float* pixels = (const float*)d_in[1];
    const float* ego    = (const float*)d_in[2];
    const float* Ww     = (const float*)d_in[3];
    const float* bw     = (const float*)d_in[4];
    const float* f0     = (const float*)d_in[5];
    const float* f1     = (const float*)d_in[6];
    const float* f2     = (const float*)d_in[7];

    float* out = (float*)d_out;
    bool fast = (d_ws != nullptr) && (ws_size >= WS_NEED);

    if (fast) {
        u16*   tf    = (u16*)d_ws;
        float* wbase = (float*)((char*)d_ws + TF_BYTES);
        float* den   = (float*)((char*)d_ws + TF_BYTES + WB_BYTES);
        prep_kernel<<<20422, 256, 0, stream>>>(cq, Ww, bw, pixels, ego,
                                               f0, f1, f2, wbase, den, tf, out);
        gather_tr_kernel<<<NQ * SCH, 256, 0, stream>>>(pixels, ego, wbase, tf, out);
        epilogue_fast_kernel<<<NQ, 256, 0, stream>>>(cq, den, out);
    } else {
        copy_zero_kernel<<<134, 256, 0, stream>>>(pixels, out);
        gather_kernel<<<18 * NQ, 256, 0, stream>>>(cq, pixels, ego, Ww, bw,
                                                   f0, f1, f2, out);
        epilogue_kernel<<<NQ, 512, 0, stream>>>(cq, pixels, ego, Ww, bw, out);
    }
}